// Round 9
// baseline (467.804 us; speedup 1.0000x reference)
//
#include <hip/hip_runtime.h>
#include <hip/hip_bf16.h>
#include <hip/hip_cooperative_groups.h>

namespace cg = cooperative_groups;

// GraphConv 2-hop: gather(ent[tail]*rel[type]) -> scatter-mean by head -> l2norm,
// twice, fused residual outputs.
//
// R2->R3: atomic scatter (92us, 17x write-amp) -> bucket counting sort: 360->251us.
// R3->R4: 8-deep unroll: NO change => not latency-bound.
// R4->R6: bf16 gather table: hops 74->57us (FETCH 230->142MB), absmax 0.03125.
// R6->R8: pair-edge hop (2 edges/wave-instr): 57->54.3us; VALUBusy 58%, BW 3.1TB/s
//         => hops ~at the random-line fabric floor for bf16 rows.
// R9: non-hop time = 115us across 7 small kernels; est. 55-70us is dispatch gaps +
//     ramp. Collapse CSR build (hist||cvt||rel, scan, place, finalize) into ONE
//     cooperative kernel with grid.sync between phases. 9 dispatches -> 3.
//
// ws (ints): packed[E] | union{staging int[E], ent1 u16[n_ent*64]} |
//            ent_bf16 u16[n_ent*64] | G[L] | Gscan[L] | bsum[128] |
//            row_start[n_ent+1] | rel1 f32[n_rel*64]
// staging dies at finalize (phase 3); ent1 born in hop1 (later launch) -> union safe.
// ent_bf16 written in phase 0 (cvt), read by hop1 -> must NOT alias staging.

#define CHUNK 8192
#define BSHIFT 8
#define BMASK 255
#define CSRB 512   // cooperative grid blocks
#define CSRT 512   // threads per block

__device__ __forceinline__ float b2f(unsigned int u16bits) {
    return __uint_as_float(u16bits << 16);
}
__device__ __forceinline__ unsigned int f2b_u32(float f) {  // bf16 bits, RNE
    unsigned int u = __float_as_uint(f);
    return (u + 0x7FFFu + ((u >> 16) & 1u)) >> 16;
}

// ---- cooperative CSR build: P0 hist||cvt||rel -> P1 scan -> P2 place -> P3 finalize
__global__ __launch_bounds__(CSRT) void csr_build_kernel(
    const int* __restrict__ heads, const int* __restrict__ tails,
    const int* __restrict__ etype, const float* __restrict__ entity_emb,
    const float* __restrict__ relation_emb,
    int* __restrict__ G, int* __restrict__ Gscan, int* __restrict__ bsum,
    int* __restrict__ staging, int* __restrict__ packed, int* __restrict__ row_start,
    unsigned int* __restrict__ ent_bf16, float* __restrict__ rel1,
    float* __restrict__ out_rel,
    int E, int nchunks, int nb, int L, int nscan, int n_ent, int n_rel)
{
    cg::grid_group grid = cg::this_grid();
    const int b = blockIdx.x;
    const int tid = threadIdx.x;
    const int lane = tid & 63;
    const int w = tid >> 6;
    __shared__ int sh[CSRT];
    __shared__ int sh2[256], sh3[256];

    // ================= P0: blocks [0,nchunks): hist | rest: cvt (+rel on last) ====
    if (b < nchunks) {
        for (int i = tid; i < nb; i += CSRT) sh[i] = 0;
        __syncthreads();
        const int lo = b * CHUNK;
        const int hi = min(lo + CHUNK, E);
        for (int i = lo + tid; i < hi; i += CSRT)
            atomicAdd(&sh[heads[i] >> BSHIFT], 1);
        __syncthreads();
        for (int i = tid; i < nb; i += CSRT) G[i * nchunks + b] = sh[i];
    } else {
        if (b == CSRB - 1) {
            // rel: rel1 = l2norm(rel0); rel2 = l2norm(rel1); out = rel0+rel1+rel2
            for (int row = w; row < n_rel; row += 8) {
                float v = relation_emb[row * 64 + lane];
                float ss = v * v;
#pragma unroll
                for (int off = 32; off > 0; off >>= 1) ss += __shfl_xor(ss, off);
                float r1v = v / fmaxf(sqrtf(ss), 1e-12f);
                float ss2 = r1v * r1v;
#pragma unroll
                for (int off = 32; off > 0; off >>= 1) ss2 += __shfl_xor(ss2, off);
                float r2v = r1v / fmaxf(sqrtf(ss2), 1e-12f);
                rel1[row * 64 + lane] = r1v;
                out_rel[row * 64 + lane] = v + r1v + r2v;
            }
        }
        // cvt f32 table -> bf16 pairs over blocks [nchunks, CSRB)
        const int ncvt = CSRB - nchunks;
        const int cb = b - nchunks;
        const int n4 = n_ent * 16;
        const uint4* in4 = (const uint4*)entity_emb;
        uint2* out2 = (uint2*)ent_bf16;
        for (int i = cb * CSRT + tid; i < n4; i += ncvt * CSRT) {
            uint4 v = in4[i];
            uint2 o;
            o.x = f2b_u32(__uint_as_float(v.x)) | (f2b_u32(__uint_as_float(v.y)) << 16);
            o.y = f2b_u32(__uint_as_float(v.z)) | (f2b_u32(__uint_as_float(v.w)) << 16);
            out2[i] = o;
        }
    }
    grid.sync();

    // ================= P1a: 512-chunk scan of G -> Gscan(partial) + bsum ==========
    if (b < nscan) {
        const int gi = b * CSRT + tid;
        int v = (gi < L) ? G[gi] : 0;
        int s = v;
#pragma unroll
        for (int off = 1; off < 64; off <<= 1) {
            int t = __shfl_up(s, off);
            if (lane >= off) s += t;
        }
        if (lane == 63) sh[w] = s;
        __syncthreads();
        if (w == 0) {
            int ws = (lane < 8) ? sh[lane] : 0;
#pragma unroll
            for (int off = 1; off < 8; off <<= 1) {
                int t = __shfl_up(ws, off);
                if (lane >= off) ws += t;
            }
            if (lane < 8) sh[lane] = ws;
            if (lane == 7) bsum[b] = ws;
        }
        __syncthreads();
        int woff = (w > 0) ? sh[w - 1] : 0;
        if (gi < L) Gscan[gi] = s - v + woff;
    }
    grid.sync();

    // ================= P1b: block 0 exclusive-scans bsum[nscan] in place ==========
    if (b == 0) {
        int v = (tid < nscan) ? bsum[tid] : 0;
        int s = v;
#pragma unroll
        for (int off = 1; off < 64; off <<= 1) {
            int t = __shfl_up(s, off);
            if (lane >= off) s += t;
        }
        if (lane == 63) sh[w] = s;
        __syncthreads();
        if (w == 0) {
            int ws = (lane < 8) ? sh[lane] : 0;
#pragma unroll
            for (int off = 1; off < 8; off <<= 1) {
                int t = __shfl_up(ws, off);
                if (lane >= off) ws += t;
            }
            if (lane < 8) sh[lane] = ws;
        }
        __syncthreads();
        int woff = (w > 0) ? sh[w - 1] : 0;
        if (tid < nscan) bsum[tid] = s - v + woff;   // exclusive block offsets
    }
    grid.sync();

    // ================= P2: place edges into disjoint (chunk,bucket) ranges ========
    if (b < nchunks) {
        for (int i = tid; i < nb; i += CSRT) {
            int idx = i * nchunks + b;
            sh[i] = Gscan[idx] + bsum[idx >> 9];
        }
        __syncthreads();
        const int lo = b * CHUNK;
        const int hi = min(lo + CHUNK, E);
        for (int i = lo + tid; i < hi; i += CSRT) {
            int h = heads[i];
            int entry = tails[i] | (etype[i] << 17) | ((h & BMASK) << 21);
            int pos = atomicAdd(&sh[h >> BSHIFT], 1);
            staging[pos] = entry;
        }
    }
    grid.sync();

    // ================= P3: per-bucket degree+scan -> row_start; CSR placement =====
    if (b < nb) {
        const int head_lo = b << BSHIFT;
        const int i0 = b * nchunks;
        const int seg_start = Gscan[i0] + bsum[i0 >> 9];
        int seg_end = E;
        if (b + 1 < nb) {
            const int i1 = (b + 1) * nchunks;
            seg_end = Gscan[i1] + bsum[i1 >> 9];
        }
        if (tid < 256) sh2[tid] = 0;                      // deg
        __syncthreads();
        for (int i = seg_start + tid; i < seg_end; i += CSRT)
            atomicAdd(&sh2[(staging[i] >> 21) & BMASK], 1);
        __syncthreads();
        if (tid < 256) sh[tid] = sh2[tid];                // pos (inclusive scan)
        __syncthreads();
        for (int off = 1; off < 256; off <<= 1) {
            int t = (tid >= off && tid < 256) ? sh[tid - off] : 0;
            __syncthreads();
            if (tid < 256) sh[tid] += t;
            __syncthreads();
        }
        if (tid < 256) {
            const int excl = sh[tid] - sh2[tid];
            const int h = head_lo + tid;
            if (h < n_ent) row_start[h] = seg_start + excl;
            sh3[tid] = seg_start + excl;                  // cur
        }
        if (b == 0 && tid == 0) row_start[n_ent] = E;
        __syncthreads();
        for (int i = seg_start + tid; i < seg_end; i += CSRT) {
            int v = staging[i];
            int p = atomicAdd(&sh3[(v >> 21) & BMASK], 1);
            packed[p] = v;
        }
    }
}

// ---- hop: one wave per row; lanes 0-31 = edge A, 32-63 = edge B; uint gathers ----
template <bool FINAL>
__global__ void hop_kernel(const unsigned int* __restrict__ ent_src,  // bf16-pair table
                           const float* __restrict__ rel_src,
                           const int* __restrict__ row_start,
                           const int* __restrict__ packed,
                           unsigned int* __restrict__ ent_next,       // FINAL=false
                           const float2* __restrict__ ent0,           // FINAL=true
                           const float2* __restrict__ drug0,          // FINAL=true
                           float2* __restrict__ out_ent,              // FINAL=true
                           float2* __restrict__ out_drug,             // FINAL=true
                           int n_rows, int n_drugs) {
    __shared__ float rel_lds[16 * 64];
    for (int i = threadIdx.x; i < 16 * 64; i += blockDim.x) rel_lds[i] = rel_src[i];
    __syncthreads();

    const int lane = threadIdx.x & 63;
    const int half = lane >> 5;
    const int c = lane & 31;
    const int wave = blockIdx.x * (blockDim.x >> 6) + (threadIdx.x >> 6);
    const int nw = gridDim.x * (blockDim.x >> 6);

    for (int r = wave; r < n_rows; r += nw) {
        const int start = row_start[r];
        const int deg = row_start[r + 1] - start;
        float a00 = 0.f, a01 = 0.f, a10 = 0.f, a11 = 0.f;
        float a20 = 0.f, a21 = 0.f, a30 = 0.f, a31 = 0.f;
        for (int base = 0; base < deg; base += 64) {
            int rem = deg - base;
            if (rem > 64) rem = 64;
            int pk = 0;
            if (lane < rem) pk = packed[start + base + lane];
            const int npairs = (rem + 1) >> 1;
            for (int i = 0; i < npairs; i += 4) {
                int e0 = 2 * (i + 0) + half;
                int e1 = 2 * (i + 1) + half;
                int e2 = 2 * (i + 2) + half;
                int e3 = 2 * (i + 3) + half;
                int p0 = __shfl(pk, e0 & 63), p1 = __shfl(pk, e1 & 63);
                int p2 = __shfl(pk, e2 & 63), p3 = __shfl(pk, e3 & 63);
                unsigned int u0 = 0, u1 = 0, u2 = 0, u3 = 0;
                if (e0 < rem) u0 = ent_src[(size_t)(p0 & 131071) * 32 + c];
                if (e1 < rem) u1 = ent_src[(size_t)(p1 & 131071) * 32 + c];
                if (e2 < rem) u2 = ent_src[(size_t)(p2 & 131071) * 32 + c];
                if (e3 < rem) u3 = ent_src[(size_t)(p3 & 131071) * 32 + c];
                const float2 r0 = *(const float2*)&rel_lds[((p0 >> 17) & 15) * 64 + 2 * c];
                const float2 r1 = *(const float2*)&rel_lds[((p1 >> 17) & 15) * 64 + 2 * c];
                const float2 r2 = *(const float2*)&rel_lds[((p2 >> 17) & 15) * 64 + 2 * c];
                const float2 r3 = *(const float2*)&rel_lds[((p3 >> 17) & 15) * 64 + 2 * c];
                a00 = fmaf(b2f(u0 & 0xFFFFu), r0.x, a00);
                a01 = fmaf(b2f(u0 >> 16), r0.y, a01);
                a10 = fmaf(b2f(u1 & 0xFFFFu), r1.x, a10);
                a11 = fmaf(b2f(u1 >> 16), r1.y, a11);
                a20 = fmaf(b2f(u2 & 0xFFFFu), r2.x, a20);
                a21 = fmaf(b2f(u2 >> 16), r2.y, a21);
                a30 = fmaf(b2f(u3 & 0xFFFFu), r3.x, a30);
                a31 = fmaf(b2f(u3 >> 16), r3.y, a31);
            }
        }
        float a0 = (a00 + a10) + (a20 + a30);
        float a1 = (a01 + a11) + (a21 + a31);
        a0 += __shfl_xor(a0, 32);
        a1 += __shfl_xor(a1, 32);
        const float denom = (float)(deg > 0 ? deg : 1);
        a0 /= denom;
        a1 /= denom;
        float ss = a0 * a0 + a1 * a1;
#pragma unroll
        for (int off = 16; off > 0; off >>= 1) ss += __shfl_xor(ss, off);
        const float inv = 1.0f / fmaxf(sqrtf(ss), 1e-12f);
        const float e2_0 = a0 * inv, e2_1 = a1 * inv;
        if (!FINAL) {
            if (half == 0)
                ent_next[(size_t)r * 32 + c] = f2b_u32(e2_0) | (f2b_u32(e2_1) << 16);
        } else {
            if (half == 0) {
                const unsigned int e1u = ent_src[(size_t)r * 32 + c];
                const float s0 = b2f(e1u & 0xFFFFu) + e2_0;
                const float s1 = b2f(e1u >> 16) + e2_1;
                const float2 base0 = ent0[(size_t)r * 32 + c];
                float2 o;
                o.x = base0.x + s0;
                o.y = base0.y + s1;
                out_ent[(size_t)r * 32 + c] = o;
                if (r < n_drugs) {
                    const float2 based = drug0[(size_t)r * 32 + c];
                    float2 od;
                    od.x = based.x + s0;
                    od.y = based.y + s1;
                    out_drug[(size_t)r * 32 + c] = od;
                }
            }
        }
    }
}

extern "C" void kernel_launch(void* const* d_in, const int* in_sizes, int n_in,
                              void* d_out, int out_size, void* d_ws, size_t ws_size,
                              hipStream_t stream) {
    const float* drug_emb = (const float*)d_in[0];
    const float* entity_emb = (const float*)d_in[1];
    const float* relation_emb = (const float*)d_in[2];
    const int* edge_index = (const int*)d_in[3];
    const int* edge_type = (const int*)d_in[4];

    const int n_drugs = in_sizes[0] / 64;   // 2000
    const int n_ent = in_sizes[1] / 64;     // 100000
    const int n_rel = in_sizes[2] / 64;     // 16
    const int E = in_sizes[4];              // 1250000

    const int* heads = edge_index;
    const int* tails = edge_index + E;

    const int nchunks = (E + CHUNK - 1) / CHUNK;          // 153
    const int nb = (n_ent + (1 << BSHIFT) - 1) >> BSHIFT; // 391
    const int L = nb * nchunks;                           // 59,823
    const int nscan = (L + CSRT - 1) / CSRT;              // 117

    // ws carve-up (int units).
    int* packed = (int*)d_ws;                                    // E
    int* unionA = packed + ((E + 1) & ~1);                       // staging | ent1
    int* staging = unionA;                                       // E (dies P3)
    unsigned int* ent1 = (unsigned int*)unionA;                  // n_ent*32 (born hop1)
    size_t unionA_ints = (size_t)n_ent * 32;                     // 3.2M >= E
    if (unionA_ints < (size_t)E) unionA_ints = (size_t)E;
    unsigned int* ent_bf16 = (unsigned int*)(unionA + unionA_ints);  // n_ent*32
    int* G = unionA + unionA_ints + (size_t)n_ent * 32;          // L
    int* Gscan = G + L;                                          // L
    int* bsum = Gscan + L;                                       // 128
    int* row_start = bsum + 128;                                 // n_ent+1
    float* rel1 = (float*)(row_start + n_ent + 1);               // n_rel*64

    float* out_ent = (float*)d_out;
    float* out_drug = out_ent + (size_t)n_ent * 64;
    float* out_rel = out_drug + (size_t)n_drugs * 64;

    int E_ = E, nchunks_ = nchunks, nb_ = nb, L_ = L, nscan_ = nscan,
        n_ent_ = n_ent, n_rel_ = n_rel;
    void* args[] = {
        (void*)&heads, (void*)&tails, (void*)&edge_type,
        (void*)&entity_emb, (void*)&relation_emb,
        (void*)&G, (void*)&Gscan, (void*)&bsum,
        (void*)&staging, (void*)&packed, (void*)&row_start,
        (void*)&ent_bf16, (void*)&rel1, (void*)&out_rel,
        (void*)&E_, (void*)&nchunks_, (void*)&nb_, (void*)&L_, (void*)&nscan_,
        (void*)&n_ent_, (void*)&n_rel_
    };
    hipLaunchCooperativeKernel((void*)csr_build_kernel, dim3(CSRB), dim3(CSRT),
                               args, 0, stream);

    hop_kernel<false><<<2048, 256, 0, stream>>>(ent_bf16, relation_emb, row_start, packed,
                                                ent1, nullptr, nullptr, nullptr, nullptr,
                                                n_ent, 0);
    hop_kernel<true><<<2048, 256, 0, stream>>>(ent1, rel1, row_start, packed,
                                               nullptr, (const float2*)entity_emb,
                                               (const float2*)drug_emb,
                                               (float2*)out_ent, (float2*)out_drug,
                                               n_ent, n_drugs);
}

// Round 13
// 221.963 us; speedup vs baseline: 2.1076x; 2.1076x over previous
//
#include <hip/hip_runtime.h>
#include <hip/hip_bf16.h>

// GraphConv 2-hop: gather(ent[tail]*rel[type]) -> scatter-mean by head -> l2norm,
// twice, fused residual outputs.
//
// R2->R3: atomic scatter (92us, 17x write-amp) -> bucket counting sort: 360->251us.
// R4->R6: bf16 gather table: hops 74->57us. R6->R8: pair-edge hop: 57->54.3us.
// R9: cooperative single-kernel CSR build REGRESSED (275us; grid.sync ~70us each on
//     MI355X). REVERTED. Lesson: kernel boundaries >> grid.sync for short phases.
// R10-R13: R8 pipeline with sync-free fusions: (hist||cvt||rel) one kernel; bsum scan
//      folded into place/finalize as a per-block 59-elem wave mini-scan. 9->6 launches.
//      (R10-R12 never ran: infra timeouts. Identical resubmit.)
//
// ws (ints): packed[E] | unionA{staging int[E], ent1 u16[n_ent*64]} |
//            ent_bf16 u16[n_ent*64] | G[L] | Gscan[L] | bsum[128] |
//            row_start[n_ent+1] | rel1 f32[n_rel*64]
// unionA safe: staging dies at finalize; ent1 born in hop1 (after finalize).

#define CHUNK 8192
#define BSHIFT 8
#define BMASK 255
#define PREB 512   // fused-pre grid blocks

__device__ __forceinline__ float b2f(unsigned int u16bits) {
    return __uint_as_float(u16bits << 16);
}
__device__ __forceinline__ unsigned int f2b_u32(float f) {  // bf16 bits, RNE
    unsigned int u = __float_as_uint(f);
    return (u + 0x7FFFu + ((u >> 16) & 1u)) >> 16;
}

// ---- K1: blocks [0,nchunks): per-chunk bucket histogram; rest: cvt; last: +rel ----
__global__ __launch_bounds__(512) void fused_pre_kernel(
    const int* __restrict__ heads, const float* __restrict__ entity_emb,
    const float* __restrict__ relation_emb,
    int* __restrict__ G, unsigned int* __restrict__ ent_bf16,
    float* __restrict__ rel1, float* __restrict__ out_rel,
    int E, int nchunks, int nb, int n_ent, int n_rel)
{
    const int b = blockIdx.x;
    const int tid = threadIdx.x;
    if (b < nchunks) {
        __shared__ int hist[512];
        for (int i = tid; i < nb; i += 512) hist[i] = 0;
        __syncthreads();
        const int lo = b * CHUNK;
        const int hi = min(lo + CHUNK, E);
        for (int i = lo + tid; i < hi; i += 512)
            atomicAdd(&hist[heads[i] >> BSHIFT], 1);
        __syncthreads();
        for (int i = tid; i < nb; i += 512) G[i * nchunks + b] = hist[i];
    } else {
        const int lane = tid & 63;
        const int w = tid >> 6;
        if (b == PREB - 1) {
            // rel1 = l2norm(rel0); rel2 = l2norm(rel1) (= rel1); out = rel0+rel1+rel2
            for (int row = w; row < n_rel; row += 8) {
                float v = relation_emb[row * 64 + lane];
                float ss = v * v;
#pragma unroll
                for (int off = 32; off > 0; off >>= 1) ss += __shfl_xor(ss, off);
                float r1v = v / fmaxf(sqrtf(ss), 1e-12f);
                float ss2 = r1v * r1v;
#pragma unroll
                for (int off = 32; off > 0; off >>= 1) ss2 += __shfl_xor(ss2, off);
                float r2v = r1v / fmaxf(sqrtf(ss2), 1e-12f);
                rel1[row * 64 + lane] = r1v;
                out_rel[row * 64 + lane] = v + r1v + r2v;
            }
        }
        const int ncvt = PREB - nchunks;
        const int cb = b - nchunks;
        const int n4 = n_ent * 16;
        const uint4* in4 = (const uint4*)entity_emb;
        uint2* out2 = (uint2*)ent_bf16;
        for (int i = cb * 512 + tid; i < n4; i += ncvt * 512) {
            uint4 v = in4[i];
            uint2 o;
            o.x = f2b_u32(__uint_as_float(v.x)) | (f2b_u32(__uint_as_float(v.y)) << 16);
            o.y = f2b_u32(__uint_as_float(v.z)) | (f2b_u32(__uint_as_float(v.w)) << 16);
            out2[i] = o;
        }
    }
}

// ---- K2: exclusive scan of G in 1024-chunks; per-block totals to bsum ----
__global__ void scan_block(const int* __restrict__ in, int* __restrict__ out_excl,
                           int* __restrict__ blocksum, int n) {
    __shared__ int wsum[16];
    const int tid = threadIdx.x;
    const int gi = blockIdx.x * 1024 + tid;
    const int lane = tid & 63, wid = tid >> 6;
    int v = (gi < n) ? in[gi] : 0;
    int s = v;
#pragma unroll
    for (int off = 1; off < 64; off <<= 1) {
        int t = __shfl_up(s, off);
        if (lane >= off) s += t;
    }
    if (lane == 63) wsum[wid] = s;
    __syncthreads();
    if (wid == 0) {
        int ws = (lane < 16) ? wsum[lane] : 0;
#pragma unroll
        for (int off = 1; off < 16; off <<= 1) {
            int t = __shfl_up(ws, off);
            if (lane >= off) ws += t;
        }
        if (lane < 16) wsum[lane] = ws;
        if (lane == 15 && blocksum) blocksum[blockIdx.x] = ws;
    }
    __syncthreads();
    int wave_off = (wid > 0) ? wsum[wid - 1] : 0;
    if (gi < n) out_excl[gi] = s - v + wave_off;
}

// ---- K3: place edges into per-(chunk,bucket) disjoint staging ranges ----
// bsum prefix computed in-block by wave 0 (nscan<=64 entries).
__global__ __launch_bounds__(512) void place_stage_kernel(
    const int* __restrict__ heads, const int* __restrict__ tails,
    const int* __restrict__ etype, const int* __restrict__ Gscan,
    const int* __restrict__ bsum,
    int* __restrict__ staging, int E, int nchunks, int nb, int nscan)
{
    __shared__ int cur[512];
    __shared__ int pref[64];
    const int blk = blockIdx.x;
    const int tid = threadIdx.x;
    if (tid < 64) {
        int v = (tid < nscan) ? bsum[tid] : 0;
        int s = v;
#pragma unroll
        for (int off = 1; off < 64; off <<= 1) {
            int t = __shfl_up(s, off);
            if (tid >= off) s += t;
        }
        pref[tid] = s - v;   // exclusive
    }
    __syncthreads();
    for (int i = tid; i < nb; i += 512) {
        int idx = i * nchunks + blk;
        cur[i] = Gscan[idx] + pref[idx >> 10];
    }
    __syncthreads();
    const int lo = blk * CHUNK;
    const int hi = min(lo + CHUNK, E);
    for (int i = lo + tid; i < hi; i += 512) {
        int h = heads[i];
        int entry = tails[i] | (etype[i] << 17) | ((h & BMASK) << 21);
        int pos = atomicAdd(&cur[h >> BSHIFT], 1);
        staging[pos] = entry;
    }
}

// ---- K4: per-bucket degree count + scan -> row_start; final CSR placement ----
__global__ __launch_bounds__(512) void finalize_kernel(
    const int* __restrict__ staging, const int* __restrict__ Gscan,
    const int* __restrict__ bsum,
    int* __restrict__ packed, int* __restrict__ row_start,
    int E, int nchunks, int nb, int nscan, int n_ent)
{
    __shared__ int deg[256], pos[256], cur[256];
    __shared__ int pref[64];
    const int b = blockIdx.x;
    const int tid = threadIdx.x;              // 512 threads
    if (tid < 64) {
        int v = (tid < nscan) ? bsum[tid] : 0;
        int s = v;
#pragma unroll
        for (int off = 1; off < 64; off <<= 1) {
            int t = __shfl_up(s, off);
            if (tid >= off) s += t;
        }
        pref[tid] = s - v;
    }
    __syncthreads();
    const int head_lo = b << BSHIFT;
    const int i0 = b * nchunks;
    const int seg_start = Gscan[i0] + pref[i0 >> 10];
    int seg_end = E;
    if (b + 1 < nb) {
        const int i1 = (b + 1) * nchunks;
        seg_end = Gscan[i1] + pref[i1 >> 10];
    }
    if (tid < 256) deg[tid] = 0;
    __syncthreads();
    for (int i = seg_start + tid; i < seg_end; i += 512)
        atomicAdd(&deg[(staging[i] >> 21) & BMASK], 1);
    __syncthreads();
    if (tid < 256) pos[tid] = deg[tid];
    __syncthreads();
    for (int off = 1; off < 256; off <<= 1) {
        int t = (tid >= off && tid < 256) ? pos[tid - off] : 0;
        __syncthreads();
        if (tid < 256) pos[tid] += t;
        __syncthreads();
    }
    if (tid < 256) {
        const int excl = pos[tid] - deg[tid];
        const int h = head_lo + tid;
        if (h < n_ent) row_start[h] = seg_start + excl;
        cur[tid] = seg_start + excl;
    }
    if (b == 0 && tid == 0) row_start[n_ent] = E;
    __syncthreads();
    for (int i = seg_start + tid; i < seg_end; i += 512) {
        int v = staging[i];
        int p = atomicAdd(&cur[(v >> 21) & BMASK], 1);
        packed[p] = v;
    }
}

// ---- hop: one wave per row; lanes 0-31 = edge A, 32-63 = edge B; uint gathers
//      (2 bf16 channels/lane, 2 edges/wave-instruction); f32 accumulation ----
template <bool FINAL>
__global__ void hop_kernel(const unsigned int* __restrict__ ent_src,  // bf16-pair table
                           const float* __restrict__ rel_src,
                           const int* __restrict__ row_start,
                           const int* __restrict__ packed,
                           unsigned int* __restrict__ ent_next,       // FINAL=false
                           const float2* __restrict__ ent0,           // FINAL=true
                           const float2* __restrict__ drug0,          // FINAL=true
                           float2* __restrict__ out_ent,              // FINAL=true
                           float2* __restrict__ out_drug,             // FINAL=true
                           int n_rows, int n_drugs) {
    __shared__ float rel_lds[16 * 64];
    for (int i = threadIdx.x; i < 16 * 64; i += blockDim.x) rel_lds[i] = rel_src[i];
    __syncthreads();

    const int lane = threadIdx.x & 63;
    const int half = lane >> 5;
    const int c = lane & 31;
    const int wave = blockIdx.x * (blockDim.x >> 6) + (threadIdx.x >> 6);
    const int nw = gridDim.x * (blockDim.x >> 6);

    for (int r = wave; r < n_rows; r += nw) {
        const int start = row_start[r];
        const int deg = row_start[r + 1] - start;
        float a00 = 0.f, a01 = 0.f, a10 = 0.f, a11 = 0.f;
        float a20 = 0.f, a21 = 0.f, a30 = 0.f, a31 = 0.f;
        for (int base = 0; base < deg; base += 64) {
            int rem = deg - base;
            if (rem > 64) rem = 64;
            int pk = 0;
            if (lane < rem) pk = packed[start + base + lane];
            const int npairs = (rem + 1) >> 1;
            for (int i = 0; i < npairs; i += 4) {
                int e0 = 2 * (i + 0) + half;
                int e1 = 2 * (i + 1) + half;
                int e2 = 2 * (i + 2) + half;
                int e3 = 2 * (i + 3) + half;
                int p0 = __shfl(pk, e0 & 63), p1 = __shfl(pk, e1 & 63);
                int p2 = __shfl(pk, e2 & 63), p3 = __shfl(pk, e3 & 63);
                unsigned int u0 = 0, u1 = 0, u2 = 0, u3 = 0;
                if (e0 < rem) u0 = ent_src[(size_t)(p0 & 131071) * 32 + c];
                if (e1 < rem) u1 = ent_src[(size_t)(p1 & 131071) * 32 + c];
                if (e2 < rem) u2 = ent_src[(size_t)(p2 & 131071) * 32 + c];
                if (e3 < rem) u3 = ent_src[(size_t)(p3 & 131071) * 32 + c];
                const float2 r0 = *(const float2*)&rel_lds[((p0 >> 17) & 15) * 64 + 2 * c];
                const float2 r1 = *(const float2*)&rel_lds[((p1 >> 17) & 15) * 64 + 2 * c];
                const float2 r2 = *(const float2*)&rel_lds[((p2 >> 17) & 15) * 64 + 2 * c];
                const float2 r3 = *(const float2*)&rel_lds[((p3 >> 17) & 15) * 64 + 2 * c];
                a00 = fmaf(b2f(u0 & 0xFFFFu), r0.x, a00);
                a01 = fmaf(b2f(u0 >> 16), r0.y, a01);
                a10 = fmaf(b2f(u1 & 0xFFFFu), r1.x, a10);
                a11 = fmaf(b2f(u1 >> 16), r1.y, a11);
                a20 = fmaf(b2f(u2 & 0xFFFFu), r2.x, a20);
                a21 = fmaf(b2f(u2 >> 16), r2.y, a21);
                a30 = fmaf(b2f(u3 & 0xFFFFu), r3.x, a30);
                a31 = fmaf(b2f(u3 >> 16), r3.y, a31);
            }
        }
        float a0 = (a00 + a10) + (a20 + a30);
        float a1 = (a01 + a11) + (a21 + a31);
        a0 += __shfl_xor(a0, 32);
        a1 += __shfl_xor(a1, 32);
        const float denom = (float)(deg > 0 ? deg : 1);
        a0 /= denom;
        a1 /= denom;
        float ss = a0 * a0 + a1 * a1;
#pragma unroll
        for (int off = 16; off > 0; off >>= 1) ss += __shfl_xor(ss, off);
        const float inv = 1.0f / fmaxf(sqrtf(ss), 1e-12f);
        const float e2_0 = a0 * inv, e2_1 = a1 * inv;
        if (!FINAL) {
            if (half == 0)
                ent_next[(size_t)r * 32 + c] = f2b_u32(e2_0) | (f2b_u32(e2_1) << 16);
        } else {
            if (half == 0) {
                const unsigned int e1u = ent_src[(size_t)r * 32 + c];
                const float s0 = b2f(e1u & 0xFFFFu) + e2_0;
                const float s1 = b2f(e1u >> 16) + e2_1;
                const float2 base0 = ent0[(size_t)r * 32 + c];
                float2 o;
                o.x = base0.x + s0;
                o.y = base0.y + s1;
                out_ent[(size_t)r * 32 + c] = o;
                if (r < n_drugs) {
                    const float2 based = drug0[(size_t)r * 32 + c];
                    float2 od;
                    od.x = based.x + s0;
                    od.y = based.y + s1;
                    out_drug[(size_t)r * 32 + c] = od;
                }
            }
        }
    }
}

extern "C" void kernel_launch(void* const* d_in, const int* in_sizes, int n_in,
                              void* d_out, int out_size, void* d_ws, size_t ws_size,
                              hipStream_t stream) {
    const float* drug_emb = (const float*)d_in[0];
    const float* entity_emb = (const float*)d_in[1];
    const float* relation_emb = (const float*)d_in[2];
    const int* edge_index = (const int*)d_in[3];
    const int* edge_type = (const int*)d_in[4];

    const int n_drugs = in_sizes[0] / 64;   // 2000
    const int n_ent = in_sizes[1] / 64;     // 100000
    const int n_rel = in_sizes[2] / 64;     // 16
    const int E = in_sizes[4];              // 1250000

    const int* heads = edge_index;
    const int* tails = edge_index + E;

    const int nchunks = (E + CHUNK - 1) / CHUNK;          // 153
    const int nb = (n_ent + (1 << BSHIFT) - 1) >> BSHIFT; // 391
    const int L = nb * nchunks;                           // 59,823
    const int nscan = (L + 1023) / 1024;                  // 59 (<=64)

    // ws carve-up (int units).
    int* packed = (int*)d_ws;                                    // E
    int* unionA = packed + ((E + 1) & ~1);                       // staging | ent1
    int* staging = unionA;                                       // E (dies at finalize)
    unsigned int* ent1 = (unsigned int*)unionA;                  // n_ent*32 (born hop1)
    size_t unionA_ints = (size_t)n_ent * 32;                     // 3.2M >= E
    if (unionA_ints < (size_t)E) unionA_ints = (size_t)E;
    unsigned int* ent_bf16 = (unsigned int*)(unionA + unionA_ints);  // n_ent*32
    int* G = unionA + unionA_ints + (size_t)n_ent * 32;          // L
    int* Gscan = G + L;                                          // L
    int* bsum = Gscan + L;                                       // 128
    int* row_start = bsum + 128;                                 // n_ent+1
    float* rel1 = (float*)(row_start + n_ent + 1);               // n_rel*64

    float* out_ent = (float*)d_out;
    float* out_drug = out_ent + (size_t)n_ent * 64;
    float* out_rel = out_drug + (size_t)n_drugs * 64;

    fused_pre_kernel<<<PREB, 512, 0, stream>>>(heads, entity_emb, relation_emb,
                                               G, ent_bf16, rel1, out_rel,
                                               E, nchunks, nb, n_ent, n_rel);
    scan_block<<<nscan, 1024, 0, stream>>>(G, Gscan, bsum, L);
    place_stage_kernel<<<nchunks, 512, 0, stream>>>(heads, tails, edge_type, Gscan,
                                                    bsum, staging, E, nchunks, nb, nscan);
    finalize_kernel<<<nb, 512, 0, stream>>>(staging, Gscan, bsum, packed, row_start,
                                            E, nchunks, nb, nscan, n_ent);
    hop_kernel<false><<<2048, 256, 0, stream>>>(ent_bf16, relation_emb, row_start, packed,
                                                ent1, nullptr, nullptr, nullptr, nullptr,
                                                n_ent, 0);
    hop_kernel<true><<<2048, 256, 0, stream>>>(ent1, rel1, row_start, packed,
                                               nullptr, (const float2*)entity_emb,
                                               (const float2*)drug_emb,
                                               (float2*)out_ent, (float2*)out_drug,
                                               n_ent, n_drugs);
}